// Round 1
// baseline (203.031 us; speedup 1.0000x reference)
//
#include <hip/hip_runtime.h>

// ChunkLayer: stable-partition row gather.
// B=4, L=8192, D=1024 fixed by the reference. nmax derived from out_size.
#define BSZ 4
#define LSEQ 8192
#define DDIM 1024
#define SCAN_TPB 1024          // 8192 / 1024 = 8 elems/thread
#define EPT (LSEQ / SCAN_TPB)  // 8

// One block per batch. Block-wide prefix sum over the 0/1 mask, then scatter
// every position into its partition slot:
//   boundary pos i   -> slot bound_prefix_excl(i)
//   nonboundary pos i-> slot total + (i - bound_prefix_excl(i))
// Writes ALL LSEQ slots per batch, so no dependence on ws initialization.
__global__ void build_idx_kernel(const int* __restrict__ mask,
                                 int* __restrict__ idx_full,
                                 int* __restrict__ counts) {
    const int b = blockIdx.x;
    const int t = threadIdx.x;
    const int4* m4 = (const int4*)(mask + b * LSEQ);

    int4 m0 = m4[t * 2];
    int4 m1 = m4[t * 2 + 1];
    int vals[EPT] = {m0.x, m0.y, m0.z, m0.w, m1.x, m1.y, m1.z, m1.w};

    int s = 0;
#pragma unroll
    for (int k = 0; k < EPT; ++k) { vals[k] = (vals[k] != 0); s += vals[k]; }

    // wave (64-lane) inclusive scan of per-thread sums
    const int lane = t & 63;
    const int wv = t >> 6;  // 16 waves
    int inc = s;
#pragma unroll
    for (int off = 1; off < 64; off <<= 1) {
        int v = __shfl_up(inc, off);
        if (lane >= off) inc += v;
    }

    __shared__ int wsum[16];
    __shared__ int woff[17];
    if (lane == 63) wsum[wv] = inc;
    __syncthreads();
    if (t == 0) {
        int acc = 0;
        for (int w = 0; w < 16; ++w) { woff[w] = acc; acc += wsum[w]; }
        woff[16] = acc;
        counts[b] = acc;
    }
    __syncthreads();

    const int total = woff[16];
    int run = woff[wv] + (inc - s);  // exclusive boundary-prefix at this thread's first elem
    const int base = t * EPT;
    int* out = idx_full + b * LSEQ;
#pragma unroll
    for (int k = 0; k < EPT; ++k) {
        const int pos = base + k;
        if (vals[k]) {
            out[run] = pos;
            ++run;
        } else {
            out[total + pos - run] = pos;
        }
    }
}

// One block per output row: copy 1024 floats (256 float4, 16 B/lane).
__global__ void gather_rows_kernel(const float* __restrict__ hid,
                                   const int* __restrict__ idx_full,
                                   const int* __restrict__ counts,
                                   float* __restrict__ out_h,
                                   float* __restrict__ out_m,
                                   int nmax) {
    const int j = blockIdx.x;
    const int b = blockIdx.y;
    const int row = idx_full[b * LSEQ + j];

    const float4* __restrict__ src =
        (const float4*)(hid + ((size_t)b * LSEQ + row) * DDIM);
    float4* __restrict__ dst =
        (float4*)(out_h + ((size_t)b * nmax + j) * DDIM);
    dst[threadIdx.x] = src[threadIdx.x];

    if (threadIdx.x == 0) {
        out_m[(size_t)b * nmax + j] = (j < counts[b]) ? 1.0f : 0.0f;
    }
}

extern "C" void kernel_launch(void* const* d_in, const int* in_sizes, int n_in,
                              void* d_out, int out_size, void* d_ws, size_t ws_size,
                              hipStream_t stream) {
    const float* hid = (const float*)d_in[0];
    const int* mask = (const int*)d_in[1];
    float* out = (float*)d_out;

    // out = [B, nmax, D] rows then [B, nmax] mask floats
    const int nmax = out_size / (BSZ * (DDIM + 1));

    int* idx_full = (int*)d_ws;                 // BSZ * LSEQ ints
    int* counts = idx_full + BSZ * LSEQ;        // BSZ ints

    build_idx_kernel<<<BSZ, SCAN_TPB, 0, stream>>>(mask, idx_full, counts);

    float* out_m = out + (size_t)BSZ * nmax * DDIM;
    gather_rows_kernel<<<dim3(nmax, BSZ), DDIM / 4, 0, stream>>>(
        hid, idx_full, counts, out, out_m, nmax);
}

// Round 2
// 202.107 us; speedup vs baseline: 1.0046x; 1.0046x over previous
//
#include <hip/hip_runtime.h>

// ChunkLayer: stable-partition row gather.
// B=4, L=8192, D=1024 fixed by the reference. nmax derived from out_size.
#define BSZ 4
#define LSEQ 8192
#define DDIM 1024
#define SCAN_TPB 1024          // 8192 / 1024 = 8 elems/thread
#define EPT (LSEQ / SCAN_TPB)  // 8
#define ROWS_PER_BLOCK 4       // gather: 1024 threads = 4 x (256-lane row copy)

// One block per batch. Block-wide prefix sum over the 0/1 mask, then scatter
// every position into its partition slot:
//   boundary pos i    -> slot bound_prefix_excl(i)
//   nonboundary pos i -> slot total + (i - bound_prefix_excl(i))
// Also writes the output validity mask (j < total) so the gather kernel is a
// pure row copy. Writes ALL LSEQ slots per batch -> no dependence on ws init.
__global__ void build_idx_kernel(const int* __restrict__ mask,
                                 int* __restrict__ idx_full,
                                 float* __restrict__ out_m,
                                 int nmax) {
    const int b = blockIdx.x;
    const int t = threadIdx.x;
    const int4* m4 = (const int4*)(mask + b * LSEQ);

    int4 m0 = m4[t * 2];
    int4 m1 = m4[t * 2 + 1];
    int vals[EPT] = {m0.x, m0.y, m0.z, m0.w, m1.x, m1.y, m1.z, m1.w};

    int s = 0;
#pragma unroll
    for (int k = 0; k < EPT; ++k) { vals[k] = (vals[k] != 0); s += vals[k]; }

    // wave (64-lane) inclusive scan of per-thread sums
    const int lane = t & 63;
    const int wv = t >> 6;  // 16 waves
    int inc = s;
#pragma unroll
    for (int off = 1; off < 64; off <<= 1) {
        int v = __shfl_up(inc, off);
        if (lane >= off) inc += v;
    }

    __shared__ int wsum[16];
    __shared__ int woff[17];
    if (lane == 63) wsum[wv] = inc;
    __syncthreads();
    if (t == 0) {
        int acc = 0;
        for (int w = 0; w < 16; ++w) { woff[w] = acc; acc += wsum[w]; }
        woff[16] = acc;
    }
    __syncthreads();

    const int total = woff[16];
    int run = woff[wv] + (inc - s);  // exclusive boundary-prefix at first elem
    const int base = t * EPT;
    int* out = idx_full + b * LSEQ;
#pragma unroll
    for (int k = 0; k < EPT; ++k) {
        const int pos = base + k;
        if (vals[k]) {
            out[run] = pos;
            ++run;
        } else {
            out[total + pos - run] = pos;
        }
    }

    // validity mask for this batch
    for (int j = t; j < nmax; j += SCAN_TPB) {
        out_m[(size_t)b * nmax + j] = (j < total) ? 1.0f : 0.0f;
    }
}

// 1024-thread blocks; each 256-lane subgroup copies one 4 KB row (float4).
__global__ void gather_rows_kernel(const float* __restrict__ hid,
                                   const int* __restrict__ idx_full,
                                   float* __restrict__ out_h,
                                   int nmax) {
    const int sub = threadIdx.x >> 8;        // 0..3
    const int lane = threadIdx.x & 255;      // 0..255
    const int j = blockIdx.x * ROWS_PER_BLOCK + sub;
    const int b = blockIdx.y;
    if (j >= nmax) return;

    const int row = idx_full[b * LSEQ + j];
    const float4* __restrict__ src =
        (const float4*)(hid + ((size_t)b * LSEQ + row) * DDIM);
    float4* __restrict__ dst =
        (float4*)(out_h + ((size_t)b * nmax + j) * DDIM);
    dst[lane] = src[lane];
}

extern "C" void kernel_launch(void* const* d_in, const int* in_sizes, int n_in,
                              void* d_out, int out_size, void* d_ws, size_t ws_size,
                              hipStream_t stream) {
    const float* hid = (const float*)d_in[0];
    const int* mask = (const int*)d_in[1];
    float* out = (float*)d_out;

    // out = [B, nmax, D] rows then [B, nmax] mask floats
    const int nmax = out_size / (BSZ * (DDIM + 1));

    int* idx_full = (int*)d_ws;  // BSZ * LSEQ ints

    float* out_m = out + (size_t)BSZ * nmax * DDIM;
    build_idx_kernel<<<BSZ, SCAN_TPB, 0, stream>>>(mask, idx_full, out_m, nmax);

    gather_rows_kernel<<<dim3((nmax + ROWS_PER_BLOCK - 1) / ROWS_PER_BLOCK, BSZ),
                         SCAN_TPB, 0, stream>>>(hid, idx_full, out, nmax);
}

// Round 4
// 193.973 us; speedup vs baseline: 1.0467x; 1.0419x over previous
//
#include <hip/hip_runtime.h>

// ChunkLayer: stable-partition row gather.
// B=4, L=8192, D=1024 fixed by the reference. nmax derived from out_size.
// Measured floor note: ~170 us of the timed window is harness reset traffic
// (512 MiB ws poison @ 81 us, d_out poison, d_in restore). Kernel share ~30 us.
#define BSZ 4
#define LSEQ 8192
#define DDIM 1024
#define SCAN_TPB 1024          // 8192 / 1024 = 8 elems/thread
#define EPT (LSEQ / SCAN_TPB)  // 8
#define ROWS_PER_BLOCK 4       // gather: 1024 threads = 4 x (256-lane row copy)

// Native clang vector type: __builtin_nontemporal_* rejects HIP_vector_type.
typedef float vfloat4 __attribute__((ext_vector_type(4)));

// One block per batch. Block-wide prefix sum over the 0/1 mask, then scatter
// every position into its partition slot:
//   boundary pos i    -> slot bound_prefix_excl(i)
//   nonboundary pos i -> slot total + (i - bound_prefix_excl(i))
// Also writes the output validity mask (j < total) so the gather kernel is a
// pure row copy. Writes ALL LSEQ slots per batch -> no dependence on ws init.
__global__ void build_idx_kernel(const int* __restrict__ mask,
                                 int* __restrict__ idx_full,
                                 float* __restrict__ out_m,
                                 int nmax) {
    const int b = blockIdx.x;
    const int t = threadIdx.x;
    const int4* m4 = (const int4*)(mask + b * LSEQ);

    int4 m0 = m4[t * 2];
    int4 m1 = m4[t * 2 + 1];
    int vals[EPT] = {m0.x, m0.y, m0.z, m0.w, m1.x, m1.y, m1.z, m1.w};

    int s = 0;
#pragma unroll
    for (int k = 0; k < EPT; ++k) { vals[k] = (vals[k] != 0); s += vals[k]; }

    // wave (64-lane) inclusive scan of per-thread sums
    const int lane = t & 63;
    const int wv = t >> 6;  // 16 waves
    int inc = s;
#pragma unroll
    for (int off = 1; off < 64; off <<= 1) {
        int v = __shfl_up(inc, off);
        if (lane >= off) inc += v;
    }

    __shared__ int wsum[16];
    __shared__ int woff[17];
    if (lane == 63) wsum[wv] = inc;
    __syncthreads();
    if (t == 0) {
        int acc = 0;
        for (int w = 0; w < 16; ++w) { woff[w] = acc; acc += wsum[w]; }
        woff[16] = acc;
    }
    __syncthreads();

    const int total = woff[16];
    int run = woff[wv] + (inc - s);  // exclusive boundary-prefix at first elem
    const int base = t * EPT;
    int* out = idx_full + b * LSEQ;
#pragma unroll
    for (int k = 0; k < EPT; ++k) {
        const int pos = base + k;
        if (vals[k]) {
            out[run] = pos;
            ++run;
        } else {
            out[total + pos - run] = pos;
        }
    }

    // validity mask for this batch
    for (int j = t; j < nmax; j += SCAN_TPB) {
        out_m[(size_t)b * nmax + j] = (j < total) ? 1.0f : 0.0f;
    }
}

// 1024-thread blocks; each 256-lane subgroup copies one 4 KB row (float4).
// Flat 1D grid over all (b, j) rows; nontemporal stores (output is never
// re-read on-device) to reduce L2/L3 write-allocate pressure.
__global__ void gather_rows_kernel(const float* __restrict__ hid,
                                   const int* __restrict__ idx_full,
                                   float* __restrict__ out_h,
                                   int nmax) {
    const int sub = threadIdx.x >> 8;        // 0..3
    const int lane = threadIdx.x & 255;      // 0..255
    const int gr = blockIdx.x * ROWS_PER_BLOCK + sub;  // global row id
    const int b = gr / nmax;
    const int j = gr - b * nmax;
    if (b >= BSZ) return;

    const int row = idx_full[b * LSEQ + j];
    const vfloat4* __restrict__ src =
        (const vfloat4*)(hid + ((size_t)b * LSEQ + row) * DDIM);
    vfloat4* __restrict__ dst =
        (vfloat4*)(out_h + ((size_t)b * nmax + j) * DDIM);
    vfloat4 v = __builtin_nontemporal_load(src + lane);
    __builtin_nontemporal_store(v, dst + lane);
}

extern "C" void kernel_launch(void* const* d_in, const int* in_sizes, int n_in,
                              void* d_out, int out_size, void* d_ws, size_t ws_size,
                              hipStream_t stream) {
    const float* hid = (const float*)d_in[0];
    const int* mask = (const int*)d_in[1];
    float* out = (float*)d_out;

    // out = [B, nmax, D] rows then [B, nmax] mask floats
    const int nmax = out_size / (BSZ * (DDIM + 1));

    int* idx_full = (int*)d_ws;  // BSZ * LSEQ ints

    float* out_m = out + (size_t)BSZ * nmax * DDIM;
    build_idx_kernel<<<BSZ, SCAN_TPB, 0, stream>>>(mask, idx_full, out_m, nmax);

    const int total_rows = BSZ * nmax;
    gather_rows_kernel<<<(total_rows + ROWS_PER_BLOCK - 1) / ROWS_PER_BLOCK,
                         SCAN_TPB, 0, stream>>>(hid, idx_full, out, nmax);
}